// Round 2
// baseline (1315.060 us; speedup 1.0000x reference)
//
#include <hip/hip_runtime.h>

#define NPTS 1024
#define NB 8
#define KNN 20
#define N3 (3*NPTS)
#define CHT 256           // total concatenated channels
#define BSX (CHT*N3)      // xfeat batch stride (floats)

// ---- workspace layout (float offsets) ----
constexpr int OFF_X0    = 0;                          // [B][3][N]
constexpr int OFF_XFEAT = OFF_X0 + NB*N3;             // [B][256][3][N]
constexpr int OFF_YAP   = OFF_XFEAT + NB*CHT*N3;      // [B][3][N][64]
constexpr int OFF_YBP   = OFF_YAP + NB*N3*64;
constexpr int OFF_YAD   = OFF_YBP + NB*N3*64;
constexpr int OFF_YBD   = OFF_YAD + NB*N3*64;
constexpr int OFF_XX    = OFF_YBD + NB*N3*64;         // [B][N]
constexpr int OFF_WCFT  = OFF_XX + NB*NPTS;           // [256][128]
constexpr int OFF_STATS = OFF_WCFT + 256*128;         // 5 layers x 256
constexpr int OFF_IDX   = OFF_STATS + 5*256;          // int32 [B][N][20]
// final stage aliases (yA*/yB* are dead after the layer loop):
constexpr int OFF_PF    = OFF_YAP;                    // [B][3][N][128] (12 MB, fits yAp+yBp)
constexpr int OFF_DF    = OFF_YAD;                    // [B][3][N]
// peak ~ 12.81M floats = 51.3 MB

// x [B][N][3] -> x0 [B][3][N]
__global__ void k_transpose(const float* __restrict__ x, float* __restrict__ x0) {
  int t = blockIdx.x*256 + threadIdx.x;
  int b = t >> 10, n = t & 1023;
  const float* p = x + t*3;
  x0[b*N3 + n]          = p[0];
  x0[b*N3 + NPTS + n]   = p[1];
  x0[b*N3 + 2*NPTS + n] = p[2];
}

// per-point squared norm over D flattened feature dims
__global__ void k_xx(const float* __restrict__ Fb, int bs, int D, float* __restrict__ xx) {
  int t = blockIdx.x*256 + threadIdx.x;
  int b = t >> 10, m = t & 1023;
  const float* f = Fb + b*bs + m;
  float a = 0.f;
  for (int d = 0; d < D; ++d) { float v = f[d*NPTS]; a = fmaf(v, v, a); }
  xx[t] = a;
}

// kNN: block handles 8 query rows; computes neg_dist for all 1024 m; top-20 per row
__global__ __launch_bounds__(256) void k_knn(const float* __restrict__ Fb, int bs, int D,
                                             const float* __restrict__ xx, int* __restrict__ idxo) {
  __shared__ float rowF[192*8];      // [d][r]
  __shared__ float dist[8*NPTS];     // [r][m]  32 KB
  int tid = threadIdx.x;
  int blk = blockIdx.x;
  int b = blk >> 7;
  int n0 = (blk & 127) * 8;
  const float* f = Fb + b*bs;
  for (int e = tid; e < D*8; e += 256)
    rowF[e] = f[(e >> 3)*NPTS + n0 + (e & 7)];
  __syncthreads();
  float acc[8][4];
  #pragma unroll
  for (int r = 0; r < 8; ++r)
    #pragma unroll
    for (int j = 0; j < 4; ++j) acc[r][j] = 0.f;
  for (int d = 0; d < D; ++d) {
    float xm[4];
    #pragma unroll
    for (int j = 0; j < 4; ++j) xm[j] = f[d*NPTS + tid + 256*j];
    #pragma unroll
    for (int r = 0; r < 8; ++r) {
      float rf = rowF[d*8 + r];
      #pragma unroll
      for (int j = 0; j < 4; ++j) acc[r][j] = fmaf(rf, xm[j], acc[r][j]);
    }
  }
  float xxm[4];
  #pragma unroll
  for (int j = 0; j < 4; ++j) xxm[j] = xx[b*NPTS + tid + 256*j];
  #pragma unroll
  for (int r = 0; r < 8; ++r) {
    float xxr = xx[b*NPTS + n0 + r];
    #pragma unroll
    for (int j = 0; j < 4; ++j)
      dist[r*NPTS + tid + 256*j] = 2.f*acc[r][j] - xxr - xxm[j];
  }
  __syncthreads();
  // top-20 per row: 8 groups of 32 lanes (groups live in wave halves -> lockstep)
  int r = tid >> 5, lane = tid & 31;
  float* dr = dist + r*NPTS;
  int* orow = idxo + (b*NPTS + n0 + r)*KNN;
  for (int it = 0; it < KNN; ++it) {
    float bv = -3.402823466e38f; int bi = NPTS;
    for (int s = 0; s < 32; ++s) {
      int m = lane + (s << 5);
      float v = dr[m];
      if (v > bv || (v == bv && m < bi)) { bv = v; bi = m; }
    }
    #pragma unroll
    for (int off = 16; off > 0; off >>= 1) {
      float ov = __shfl_xor(bv, off, 32);
      int   oi = __shfl_xor(bi, off, 32);
      if (ov > bv || (ov == bv && oi < bi)) { bv = ov; bi = oi; }
    }
    if (lane == 0) { orow[it] = bi; dr[bi] = -3.402823466e38f; }
  }
}

// yA[b][v][n][o] = sum_i w[o][i] * x[b][i][v][n]
// yB[b][v][n][o] = sum_i (w[o][DIN+i]-w[o][i]) * x[b][i][v][n]
template<int DIN>
__global__ __launch_bounds__(256) void k_linear(const float* __restrict__ xin, int bsx,
                                                const float* __restrict__ w,
                                                float* __restrict__ yA, float* __restrict__ yB) {
  __shared__ float wA[64*65], wB[64*65];
  int tid = threadIdx.x;
  for (int e = tid; e < 64*DIN; e += 256) {
    int o = e / DIN, i = e % DIN;
    float a = w[o*(2*DIN) + i];
    wA[o*65 + i] = a;
    wB[o*65 + i] = w[o*(2*DIN) + DIN + i] - a;
  }
  __syncthreads();
  int o = tid & 63, ns = tid >> 6;
  int b = blockIdx.y / 3, v = blockIdx.y % 3;
  int n0 = blockIdx.x * 64;
  const float* xb = xin + b*bsx + v*NPTS;
  for (int j = 0; j < 16; ++j) {
    int n = n0 + ns + 4*j;
    float ap = 0.f, bp = 0.f;
    #pragma unroll 4
    for (int i = 0; i < DIN; ++i) {
      float xv = xb[i*N3 + n];
      ap = fmaf(wA[o*65 + i], xv, ap);
      bp = fmaf(wB[o*65 + i], xv, bp);
    }
    int oi = ((b*3 + v)*NPTS + n)*64 + o;
    yA[oi] = ap; yB[oi] = bp;
  }
}

// accumulate per-channel sum / sumsq of ||p||+eps over all (b,n,k)
__global__ __launch_bounds__(256) void k_stats(const float* __restrict__ yAp, const float* __restrict__ yBp,
                                               const int* __restrict__ idxo, float* __restrict__ statsL) {
  __shared__ float rs[256], rss[256];
  int tid = threadIdx.x; int o = tid & 63, w = tid >> 6;
  int blk = blockIdx.x;
  int b = blk >> 6;
  int n0 = (blk & 63) << 4;
  float s = 0.f, ss = 0.f;
  for (int jj = 0; jj < 4; ++jj) {
    int n = n0 + w + (jj << 2);
    int i0 = (b*3*NPTS + n)*64 + o;
    float c0 = yBp[i0], c1 = yBp[i0 + NPTS*64], c2 = yBp[i0 + 2*NPTS*64];
    const int* ir = idxo + (b*NPTS + n)*KNN;
    for (int kk = 0; kk < KNN; ++kk) {
      int m = ir[kk];
      int g = (b*3*NPTS + m)*64 + o;
      float p0 = yAp[g] + c0;
      float p1 = yAp[g + NPTS*64] + c1;
      float p2 = yAp[g + 2*NPTS*64] + c2;
      float nrm = sqrtf(p0*p0 + p1*p1 + p2*p2) + 1e-6f;
      s += nrm; ss = fmaf(nrm, nrm, ss);
    }
  }
  rs[tid] = s; rss[tid] = ss;
  __syncthreads();
  if (tid < 64) {
    float a  = rs[tid]  + rs[tid+64]  + rs[tid+128]  + rs[tid+192];
    float as = rss[tid] + rss[tid+64] + rss[tid+128] + rss[tid+192];
    atomicAdd(&statsL[tid], a);
    atomicAdd(&statsL[128 + tid], as);
  }
}

// BN + directional LeakyReLU + mean over k -> xfeat slice
__global__ __launch_bounds__(256) void k_apply(const float* __restrict__ yAp, const float* __restrict__ yBp,
                                               const float* __restrict__ yAd, const float* __restrict__ yBd,
                                               const int* __restrict__ idxo, const float* __restrict__ statsL,
                                               const float* __restrict__ bnw, const float* __restrict__ bnb,
                                               float* __restrict__ xfeat, int coff) {
  int tid = threadIdx.x; int o = tid & 63, w = tid >> 6;
  int blk = blockIdx.x;
  int b = blk >> 8;
  int n = ((blk & 255) << 2) + w;
  const float cntInv = 1.f / 163840.f;
  float mean = statsL[o] * cntInv;
  float var  = statsL[128 + o] * cntInv - mean*mean;
  float istd = rsqrtf(var + 1e-5f);
  float wN = bnw[o], bN = bnb[o];
  int i0 = (b*3*NPTS + n)*64 + o;
  float cp0 = yBp[i0], cp1 = yBp[i0 + NPTS*64], cp2 = yBp[i0 + 2*NPTS*64];
  float cd0 = yBd[i0], cd1 = yBd[i0 + NPTS*64], cd2 = yBd[i0 + 2*NPTS*64];
  const int* ir = idxo + (b*NPTS + n)*KNN;
  float a0 = 0.f, a1 = 0.f, a2 = 0.f;
  for (int kk = 0; kk < KNN; ++kk) {
    int m = ir[kk];
    int g = (b*3*NPTS + m)*64 + o;
    float p0 = yAp[g] + cp0, p1 = yAp[g + NPTS*64] + cp1, p2 = yAp[g + 2*NPTS*64] + cp2;
    float d0 = yAd[g] + cd0, d1 = yAd[g + NPTS*64] + cd1, d2 = yAd[g + 2*NPTS*64] + cd2;
    float nrm = sqrtf(p0*p0 + p1*p1 + p2*p2) + 1e-6f;
    float sc = ((nrm - mean)*istd*wN + bN) / nrm;
    p0 *= sc; p1 *= sc; p2 *= sc;
    float dot = p0*d0 + p1*d1 + p2*d2;
    float dsq = d0*d0 + d1*d1 + d2*d2;
    float coef = (dot < 0.f) ? (0.8f * dot / (dsq + 1e-6f)) : 0.f;
    a0 += p0 - coef*d0; a1 += p1 - coef*d1; a2 += p2 - coef*d2;
  }
  int ob = ((b*CHT + coff + o)*3)*NPTS + n;
  xfeat[ob]          = a0 * 0.05f;
  xfeat[ob + NPTS]   = a1 * 0.05f;
  xfeat[ob + 2*NPTS] = a2 * 0.05f;
}

// wcf [128][256] -> wT [256][128]
__global__ void k_wcfT(const float* __restrict__ wcf, float* __restrict__ wT) {
  int e = blockIdx.x*256 + threadIdx.x;
  int o = e >> 8, i = e & 255;
  wT[i*128 + o] = wcf[e];
}

// pF[b][v][n][o] = sum_i wcf[o][i] * cat[b][i][v][n]
__global__ __launch_bounds__(256) void k_pF(const float* __restrict__ xfeat, const float* __restrict__ wT,
                                            float* __restrict__ pF) {
  int tid = threadIdx.x; int o = tid & 127, half = tid >> 7;
  int b = blockIdx.y / 3, v = blockIdx.y % 3;
  int n0 = blockIdx.x*8 + half*4;
  const float* xb = xfeat + b*BSX + v*NPTS + n0;
  float a0 = 0.f, a1 = 0.f, a2 = 0.f, a3 = 0.f;
  for (int i = 0; i < 256; ++i) {
    float wv = wT[i*128 + o];
    const float* xp = xb + i*N3;
    a0 = fmaf(wv, xp[0], a0);
    a1 = fmaf(wv, xp[1], a1);
    a2 = fmaf(wv, xp[2], a2);
    a3 = fmaf(wv, xp[3], a3);
  }
  int ob = ((b*3 + v)*NPTS + n0)*128 + o;
  pF[ob] = a0; pF[ob + 128] = a1; pF[ob + 256] = a2; pF[ob + 384] = a3;
}

// dF[b][v][n] = sum_i wcd[i] * cat[b][i][v][n]
__global__ void k_dF(const float* __restrict__ xfeat, const float* __restrict__ wcd,
                     float* __restrict__ dF) {
  int t = blockIdx.x*256 + threadIdx.x;
  int b = t / N3, rem = t % N3;
  const float* xb = xfeat + b*BSX + rem;
  float a = 0.f;
  for (int i = 0; i < 256; ++i) a = fmaf(wcd[i], xb[i*N3], a);
  dF[t] = a;
}

__global__ __launch_bounds__(256) void k_statsF(const float* __restrict__ pF, float* __restrict__ statsF) {
  int tid = threadIdx.x; int o = tid & 127, half = tid >> 7;
  int blk = blockIdx.x;
  int b = blk >> 4, n0 = (blk & 15) << 6;
  float s = 0.f, ss = 0.f;
  for (int j = 0; j < 32; ++j) {
    int n = n0 + half + (j << 1);
    int g = (b*3*NPTS + n)*128 + o;
    float p0 = pF[g], p1 = pF[g + NPTS*128], p2 = pF[g + 2*NPTS*128];
    float nrm = sqrtf(p0*p0 + p1*p1 + p2*p2) + 1e-6f;
    s += nrm; ss = fmaf(nrm, nrm, ss);
  }
  atomicAdd(&statsF[o], s);
  atomicAdd(&statsF[128 + o], ss);
}

__global__ __launch_bounds__(256) void k_final(const float* __restrict__ pF, const float* __restrict__ dF,
                                               const float* __restrict__ statsF,
                                               const float* __restrict__ bncw, const float* __restrict__ bncb,
                                               float* __restrict__ out) {
  int tid = threadIdx.x; int o = tid & 127, half = tid >> 7;
  int blk = blockIdx.x;
  int b = blk >> 3, n0 = (blk & 7) << 7;
  const float cntInv = 1.f / 8192.f;
  float mean = statsF[o] * cntInv;
  float var  = statsF[128 + o] * cntInv - mean*mean;
  float istd = rsqrtf(var + 1e-5f);
  float wN = bncw[o], bN = bncb[o];
  float a0 = 0.f, a1 = 0.f, a2 = 0.f;
  for (int j = 0; j < 64; ++j) {
    int n = n0 + half + (j << 1);
    int g = (b*3*NPTS + n)*128 + o;
    float p0 = pF[g], p1 = pF[g + NPTS*128], p2 = pF[g + 2*NPTS*128];
    int dg = b*N3 + n;
    float d0 = dF[dg], d1 = dF[dg + NPTS], d2 = dF[dg + 2*NPTS];
    float nrm = sqrtf(p0*p0 + p1*p1 + p2*p2) + 1e-6f;
    float sc = ((nrm - mean)*istd*wN + bN) / nrm;
    p0 *= sc; p1 *= sc; p2 *= sc;
    float dot = p0*d0 + p1*d1 + p2*d2;
    float dsq = d0*d0 + d1*d1 + d2*d2;
    float coef = (dot < 0.f) ? (0.8f * dot / (dsq + 1e-6f)) : 0.f;
    a0 += p0 - coef*d0; a1 += p1 - coef*d1; a2 += p2 - coef*d2;
  }
  float scl = 1.f / 1024.f;
  int ob = (b*128 + o)*3;
  atomicAdd(&out[ob],     a0*scl);
  atomicAdd(&out[ob + 1], a1*scl);
  atomicAdd(&out[ob + 2], a2*scl);
}

extern "C" void kernel_launch(void* const* d_in, const int* in_sizes, int n_in,
                              void* d_out, int out_size, void* d_ws, size_t ws_size,
                              hipStream_t stream) {
  (void)in_sizes; (void)n_in; (void)ws_size;
  const float* x = (const float*)d_in[0];
  const float* wF[4]  = {(const float*)d_in[1],  (const float*)d_in[5],
                         (const float*)d_in[9],  (const float*)d_in[13]};
  const float* wD[4]  = {(const float*)d_in[2],  (const float*)d_in[6],
                         (const float*)d_in[10], (const float*)d_in[14]};
  const float* bnW[4] = {(const float*)d_in[3],  (const float*)d_in[7],
                         (const float*)d_in[11], (const float*)d_in[15]};
  const float* bnB[4] = {(const float*)d_in[4],  (const float*)d_in[8],
                         (const float*)d_in[12], (const float*)d_in[16]};
  const float* wcf  = (const float*)d_in[17];
  const float* wcd  = (const float*)d_in[18];
  const float* bncw = (const float*)d_in[19];
  const float* bncb = (const float*)d_in[20];

  float* ws    = (float*)d_ws;
  float* x0    = ws + OFF_X0;
  float* xfeat = ws + OFF_XFEAT;
  float* yAp   = ws + OFF_YAP;
  float* yBp   = ws + OFF_YBP;
  float* yAd   = ws + OFF_YAD;
  float* yBd   = ws + OFF_YBD;
  float* pF    = ws + OFF_PF;   // aliases yAp/yBp (dead by then)
  float* dF    = ws + OFF_DF;   // aliases yAd
  float* xx    = ws + OFF_XX;
  float* wT    = ws + OFF_WCFT;
  float* stats = ws + OFF_STATS;
  int*   idx   = (int*)(ws + OFF_IDX);

  hipMemsetAsync(stats, 0, 5*256*sizeof(float), stream);
  hipMemsetAsync(d_out, 0, (size_t)out_size*sizeof(float), stream);

  k_transpose<<<NB*NPTS/256, 256, 0, stream>>>(x, x0);
  k_wcfT<<<128, 256, 0, stream>>>(wcf, wT);

  for (int L = 0; L < 4; ++L) {
    const float* fin = (L == 0) ? x0 : (xfeat + (L-1)*64*N3);
    int bs = (L == 0) ? N3 : BSX;
    int D  = (L == 0) ? 3 : 192;
    k_xx<<<NB*NPTS/256, 256, 0, stream>>>(fin, bs, D, xx);
    k_knn<<<NB*NPTS/8, 256, 0, stream>>>(fin, bs, D, xx, idx);
    if (L == 0) {
      k_linear<1><<<dim3(16, 24), 256, 0, stream>>>(fin, bs, wF[0], yAp, yBp);
      k_linear<1><<<dim3(16, 24), 256, 0, stream>>>(fin, bs, wD[0], yAd, yBd);
    } else {
      k_linear<64><<<dim3(16, 24), 256, 0, stream>>>(fin, bs, wF[L], yAp, yBp);
      k_linear<64><<<dim3(16, 24), 256, 0, stream>>>(fin, bs, wD[L], yAd, yBd);
    }
    k_stats<<<512, 256, 0, stream>>>(yAp, yBp, idx, stats + L*256);
    k_apply<<<2048, 256, 0, stream>>>(yAp, yBp, yAd, yBd, idx, stats + L*256,
                                      bnW[L], bnB[L], xfeat, L*64);
  }

  k_pF<<<dim3(128, 24), 256, 0, stream>>>(xfeat, wT, pF);
  k_dF<<<NB*N3/256, 256, 0, stream>>>(xfeat, wcd, dF);
  k_statsF<<<128, 256, 0, stream>>>(pF, stats + 4*256);
  k_final<<<64, 256, 0, stream>>>(pF, dF, stats + 4*256, bncw, bncb, (float*)d_out);
}

// Round 3
// 1088.368 us; speedup vs baseline: 1.2083x; 1.2083x over previous
//
#include <hip/hip_runtime.h>

#define NPTS 1024
#define NB 8
#define KNN 20
#define N3 (3*NPTS)
#define CHT 256           // total concatenated channels
#define BSX (CHT*N3)      // xfeat batch stride (floats)

// ---- workspace layout (float offsets) ----
constexpr int OFF_X0    = 0;                          // [B][3][N]
constexpr int OFF_XFEAT = OFF_X0 + NB*N3;             // [B][256][3][N]
constexpr int OFF_YAP   = OFF_XFEAT + NB*CHT*N3;      // [B][3][N][64]
constexpr int OFF_YBP   = OFF_YAP + NB*N3*64;
constexpr int OFF_YAD   = OFF_YBP + NB*N3*64;
constexpr int OFF_YBD   = OFF_YAD + NB*N3*64;
constexpr int OFF_XX    = OFF_YBD + NB*N3*64;         // [B][N]
constexpr int OFF_WCFT  = OFF_XX + NB*NPTS;           // [256][128]
constexpr int OFF_STATS = OFF_WCFT + 256*128;         // 5 layers x 256
constexpr int OFF_IDX   = OFF_STATS + 5*256;          // int32 [B][N][20]
// final stage aliases (yA*/yB* dead after the layer loop):
constexpr int OFF_PF    = OFF_YAP;                    // [B][3][N][128]
constexpr int OFF_DF    = OFF_YAD;                    // [B][3][N]

// x [B][N][3] -> x0 [B][3][N]
__global__ void k_transpose(const float* __restrict__ x, float* __restrict__ x0) {
  int t = blockIdx.x*256 + threadIdx.x;
  int b = t >> 10, n = t & 1023;
  const float* p = x + t*3;
  x0[b*N3 + n]          = p[0];
  x0[b*N3 + NPTS + n]   = p[1];
  x0[b*N3 + 2*NPTS + n] = p[2];
}

// per-point squared norm over D flattened feature dims (ascending-d fmaf chain;
// k_knn2's Gram diagonal uses the identical chain -> self-dist exactly 0)
__global__ void k_xx(const float* __restrict__ Fb, int bs, int D, float* __restrict__ xx) {
  int t = blockIdx.x*256 + threadIdx.x;
  int b = t >> 10, m = t & 1023;
  const float* f = Fb + b*bs + m;
  float a = 0.f;
  for (int d = 0; d < D; ++d) { float v = f[d*NPTS]; a = fmaf(v, v, a); }
  xx[t] = a;
}

// kNN v2: 512 blocks x 512 threads. Block = 16 query rows of one batch.
// Feature panel streamed through a 32 KB LDS tile (8 d x 1024 m); Gram in regs;
// neg-dist in regs; in-register top-20 with 64-lane butterfly per row.
__global__ __launch_bounds__(512) void k_knn2(const float* __restrict__ Fb, int bs, int D,
                                              const float* __restrict__ xx,
                                              int* __restrict__ idxo) {
  __shared__ float xs[8][NPTS];          // 32 KB
  int g  = blockIdx.x;                   // 512 blocks
  int wg = (g & 7)*64 + (g >> 3);        // bijective XCD swizzle: batch b -> one XCD
  int b  = wg >> 6;                      // 8 batches x 64 blocks
  int n0 = (wg & 63) << 4;               // 16 rows per block
  int tid = threadIdx.x;
  int w = tid >> 6, lane = tid & 63;
  const float* f = Fb + b*bs;

  int row0 = n0 + 2*w, row1 = row0 + 1;
  float acc0[16], acc1[16];
  #pragma unroll
  for (int s = 0; s < 16; ++s) { acc0[s] = 0.f; acc1[s] = 0.f; }

  int nt = (D + 7) >> 3;
  for (int t = 0; t < nt; ++t) {
    int d0 = t << 3;
    int cnt = D - d0; if (cnt > 8) cnt = 8;
    __syncthreads();                     // previous tile fully consumed
    #pragma unroll
    for (int u = 0; u < 4; ++u) {
      int e = tid + (u << 9);            // 0..2047
      int dd = e >> 8, mq = (e & 255) << 2;
      if (dd < cnt)
        *(float4*)&xs[dd][mq] = *(const float4*)&f[(d0 + dd)*NPTS + mq];
    }
    __syncthreads();
    for (int dd = 0; dd < cnt; ++dd) {
      float rf0 = xs[dd][row0];
      float rf1 = xs[dd][row1];
      #pragma unroll
      for (int s2 = 0; s2 < 4; ++s2) {
        float4 xm = *(const float4*)&xs[dd][(lane << 2) + (s2 << 8)];
        acc0[s2*4+0] = fmaf(rf0, xm.x, acc0[s2*4+0]);
        acc0[s2*4+1] = fmaf(rf0, xm.y, acc0[s2*4+1]);
        acc0[s2*4+2] = fmaf(rf0, xm.z, acc0[s2*4+2]);
        acc0[s2*4+3] = fmaf(rf0, xm.w, acc0[s2*4+3]);
        acc1[s2*4+0] = fmaf(rf1, xm.x, acc1[s2*4+0]);
        acc1[s2*4+1] = fmaf(rf1, xm.y, acc1[s2*4+1]);
        acc1[s2*4+2] = fmaf(rf1, xm.z, acc1[s2*4+2]);
        acc1[s2*4+3] = fmaf(rf1, xm.w, acc1[s2*4+3]);
      }
    }
  }

  // convert to neg_dist, same op order as reference: (2*G - xx_row) - xx_m
  float xxm[16];
  #pragma unroll
  for (int s2 = 0; s2 < 4; ++s2) {
    float4 xv = *(const float4*)&xx[b*NPTS + (lane << 2) + (s2 << 8)];
    xxm[s2*4+0] = xv.x; xxm[s2*4+1] = xv.y; xxm[s2*4+2] = xv.z; xxm[s2*4+3] = xv.w;
  }
  float xxr0 = xx[b*NPTS + row0];
  float xxr1 = xx[b*NPTS + row1];
  #pragma unroll
  for (int s = 0; s < 16; ++s) {
    acc0[s] = (2.f*acc0[s] - xxr0) - xxm[s];
    acc1[s] = (2.f*acc1[s] - xxr1) - xxm[s];
  }

  // top-20 per row; lane owns m = 4*lane + 256*(s>>2) + (s&3), ascending in s.
  #pragma unroll
  for (int rr = 0; rr < 2; ++rr) {
    int rown = rr ? row1 : row0;
    unsigned taken = 0u;
    int winm = 0;
    for (int it = 0; it < KNN; ++it) {
      float bv = -3.402823466e38f;
      int   bi = 0x7fffffff;
      int   bsl = 0;
      #pragma unroll
      for (int s = 0; s < 16; ++s) {
        int m = (lane << 2) + ((s >> 2) << 8) + (s & 3);
        float v = rr ? acc1[s] : acc0[s];
        bool ok = (((taken >> s) & 1u) == 0u) && (v > bv);   // strict > keeps lowest m
        bv  = ok ? v : bv;
        bi  = ok ? m : bi;
        bsl = ok ? s : bsl;
      }
      int myi = bi, mysl = bsl;
      #pragma unroll
      for (int off = 1; off < 64; off <<= 1) {
        float ov = __shfl_xor(bv, off, 64);
        int   oi = __shfl_xor(bi, off, 64);
        bool tk = (ov > bv) || (ov == bv && oi < bi);        // tie -> lowest index
        bv = tk ? ov : bv;
        bi = tk ? oi : bi;
      }
      if (bi == myi) taken |= (1u << (mysl & 15));           // unique owner marks slot
      if (lane == it) winm = bi;
    }
    if (lane < KNN) idxo[(b*NPTS + rown)*KNN + lane] = winm;
  }
}

// yA[b][v][n][o] = sum_i w[o][i] * x[b][i][v][n]
// yB[b][v][n][o] = sum_i (w[o][DIN+i]-w[o][i]) * x[b][i][v][n]
// i-outer / 16-consecutive-n per thread: 2 LDS reads + 4 float4 loads + 32 FMA per i.
template<int DIN>
__global__ __launch_bounds__(256) void k_linear3(const float* __restrict__ xin, int bsx,
                                                 const float* __restrict__ w,
                                                 float* __restrict__ yA, float* __restrict__ yB) {
  __shared__ float wA[DIN*64], wB[DIN*64];
  int tid = threadIdx.x;
  for (int e = tid; e < 64*DIN; e += 256) {
    int o = e & 63, i = e >> 6;
    float a = w[o*(2*DIN) + i];
    wA[i*64 + o] = a;
    wB[i*64 + o] = w[o*(2*DIN) + DIN + i] - a;
  }
  __syncthreads();
  int o = tid & 63, ns = tid >> 6;
  int b = blockIdx.y / 3, v = blockIdx.y % 3;
  int n0 = blockIdx.x * 64 + ns * 16;
  const float* xb = xin + b*bsx + v*NPTS + n0;
  float ap[16], bp[16];
  #pragma unroll
  for (int j = 0; j < 16; ++j) { ap[j] = 0.f; bp[j] = 0.f; }
  for (int i = 0; i < DIN; ++i) {
    float wa = wA[i*64 + o], wb = wB[i*64 + o];
    #pragma unroll
    for (int q = 0; q < 4; ++q) {
      float4 xv = *(const float4*)&xb[i*N3 + q*4];
      ap[q*4+0] = fmaf(wa, xv.x, ap[q*4+0]); bp[q*4+0] = fmaf(wb, xv.x, bp[q*4+0]);
      ap[q*4+1] = fmaf(wa, xv.y, ap[q*4+1]); bp[q*4+1] = fmaf(wb, xv.y, bp[q*4+1]);
      ap[q*4+2] = fmaf(wa, xv.z, ap[q*4+2]); bp[q*4+2] = fmaf(wb, xv.z, bp[q*4+2]);
      ap[q*4+3] = fmaf(wa, xv.w, ap[q*4+3]); bp[q*4+3] = fmaf(wb, xv.w, bp[q*4+3]);
    }
  }
  int base = ((b*3 + v)*NPTS + n0)*64 + o;
  #pragma unroll
  for (int j = 0; j < 16; ++j) { yA[base + j*64] = ap[j]; yB[base + j*64] = bp[j]; }
}

// accumulate per-channel sum / sumsq of ||p||+eps over all (b,n,k)
__global__ __launch_bounds__(256) void k_stats(const float* __restrict__ yAp, const float* __restrict__ yBp,
                                               const int* __restrict__ idxo, float* __restrict__ statsL) {
  __shared__ float rs[256], rss[256];
  int tid = threadIdx.x; int o = tid & 63, w = tid >> 6;
  int blk = blockIdx.x;
  int b = blk >> 6;
  int n0 = (blk & 63) << 4;
  float s = 0.f, ss = 0.f;
  for (int jj = 0; jj < 4; ++jj) {
    int n = n0 + w + (jj << 2);
    int i0 = (b*3*NPTS + n)*64 + o;
    float c0 = yBp[i0], c1 = yBp[i0 + NPTS*64], c2 = yBp[i0 + 2*NPTS*64];
    const int* ir = idxo + (b*NPTS + n)*KNN;
    for (int kk = 0; kk < KNN; ++kk) {
      int m = ir[kk];
      int g = (b*3*NPTS + m)*64 + o;
      float p0 = yAp[g] + c0;
      float p1 = yAp[g + NPTS*64] + c1;
      float p2 = yAp[g + 2*NPTS*64] + c2;
      float nrm = sqrtf(p0*p0 + p1*p1 + p2*p2) + 1e-6f;
      s += nrm; ss = fmaf(nrm, nrm, ss);
    }
  }
  rs[tid] = s; rss[tid] = ss;
  __syncthreads();
  if (tid < 64) {
    float a  = rs[tid]  + rs[tid+64]  + rs[tid+128]  + rs[tid+192];
    float as = rss[tid] + rss[tid+64] + rss[tid+128] + rss[tid+192];
    atomicAdd(&statsL[tid], a);
    atomicAdd(&statsL[128 + tid], as);
  }
}

// BN + directional LeakyReLU + mean over k -> xfeat slice
__global__ __launch_bounds__(256) void k_apply(const float* __restrict__ yAp, const float* __restrict__ yBp,
                                               const float* __restrict__ yAd, const float* __restrict__ yBd,
                                               const int* __restrict__ idxo, const float* __restrict__ statsL,
                                               const float* __restrict__ bnw, const float* __restrict__ bnb,
                                               float* __restrict__ xfeat, int coff) {
  int tid = threadIdx.x; int o = tid & 63, w = tid >> 6;
  int blk = blockIdx.x;
  int b = blk >> 8;
  int n = ((blk & 255) << 2) + w;
  const float cntInv = 1.f / 163840.f;
  float mean = statsL[o] * cntInv;
  float var  = statsL[128 + o] * cntInv - mean*mean;
  float istd = rsqrtf(var + 1e-5f);
  float wN = bnw[o], bN = bnb[o];
  int i0 = (b*3*NPTS + n)*64 + o;
  float cp0 = yBp[i0], cp1 = yBp[i0 + NPTS*64], cp2 = yBp[i0 + 2*NPTS*64];
  float cd0 = yBd[i0], cd1 = yBd[i0 + NPTS*64], cd2 = yBd[i0 + 2*NPTS*64];
  const int* ir = idxo + (b*NPTS + n)*KNN;
  float a0 = 0.f, a1 = 0.f, a2 = 0.f;
  for (int kk = 0; kk < KNN; ++kk) {
    int m = ir[kk];
    int g = (b*3*NPTS + m)*64 + o;
    float p0 = yAp[g] + cp0, p1 = yAp[g + NPTS*64] + cp1, p2 = yAp[g + 2*NPTS*64] + cp2;
    float d0 = yAd[g] + cd0, d1 = yAd[g + NPTS*64] + cd1, d2 = yAd[g + 2*NPTS*64] + cd2;
    float nrm = sqrtf(p0*p0 + p1*p1 + p2*p2) + 1e-6f;
    float sc = ((nrm - mean)*istd*wN + bN) / nrm;
    p0 *= sc; p1 *= sc; p2 *= sc;
    float dot = p0*d0 + p1*d1 + p2*d2;
    float dsq = d0*d0 + d1*d1 + d2*d2;
    float coef = (dot < 0.f) ? (0.8f * dot / (dsq + 1e-6f)) : 0.f;
    a0 += p0 - coef*d0; a1 += p1 - coef*d1; a2 += p2 - coef*d2;
  }
  int ob = ((b*CHT + coff + o)*3)*NPTS + n;
  xfeat[ob]          = a0 * 0.05f;
  xfeat[ob + NPTS]   = a1 * 0.05f;
  xfeat[ob + 2*NPTS] = a2 * 0.05f;
}

// wcf [128][256] -> wT [256][128]
__global__ void k_wcfT(const float* __restrict__ wcf, float* __restrict__ wT) {
  int e = blockIdx.x*256 + threadIdx.x;
  int o = e >> 8, i = e & 255;
  wT[i*128 + o] = wcf[e];
}

// pF[b][v][n][o] = sum_i wcf[o][i] * cat[b][i][v][n]; x-tile staged in LDS
__global__ __launch_bounds__(256) void k_pF2(const float* __restrict__ xfeat, const float* __restrict__ wT,
                                             float* __restrict__ pF) {
  __shared__ float xs[256][32];          // 32 KB
  int tid = threadIdx.x;
  int b = blockIdx.y / 3, v = blockIdx.y % 3;
  int n0 = blockIdx.x * 32;
  const float* xb = xfeat + b*BSX + v*NPTS + n0;
  #pragma unroll
  for (int u = 0; u < 8; ++u) {
    int e = tid + (u << 8);              // 0..2047
    int i = e >> 3, sl = (e & 7) << 2;
    *(float4*)&xs[i][sl] = *(const float4*)&xb[i*N3 + sl];
  }
  __syncthreads();
  int o = tid & 127, h = tid >> 7;
  float a[16];
  #pragma unroll
  for (int j = 0; j < 16; ++j) a[j] = 0.f;
  for (int i = 0; i < 256; ++i) {
    float wv = wT[i*128 + o];
    #pragma unroll
    for (int q = 0; q < 4; ++q) {
      float4 xv = *(const float4*)&xs[i][h*16 + q*4];
      a[q*4+0] = fmaf(wv, xv.x, a[q*4+0]);
      a[q*4+1] = fmaf(wv, xv.y, a[q*4+1]);
      a[q*4+2] = fmaf(wv, xv.z, a[q*4+2]);
      a[q*4+3] = fmaf(wv, xv.w, a[q*4+3]);
    }
  }
  int base = ((b*3 + v)*NPTS + n0 + h*16)*128 + o;
  #pragma unroll
  for (int j = 0; j < 16; ++j) pF[base + j*128] = a[j];
}

// dF[b][v][n] = sum_i wcd[i] * cat[b][i][v][n]
__global__ void k_dF(const float* __restrict__ xfeat, const float* __restrict__ wcd,
                     float* __restrict__ dF) {
  int t = blockIdx.x*256 + threadIdx.x;
  int b = t / N3, rem = t % N3;
  const float* xb = xfeat + b*BSX + rem;
  float a = 0.f;
  for (int i = 0; i < 256; ++i) a = fmaf(wcd[i], xb[i*N3], a);
  dF[t] = a;
}

__global__ __launch_bounds__(256) void k_statsF(const float* __restrict__ pF, float* __restrict__ statsF) {
  int tid = threadIdx.x; int o = tid & 127, half = tid >> 7;
  int blk = blockIdx.x;
  int b = blk >> 4, n0 = (blk & 15) << 6;
  float s = 0.f, ss = 0.f;
  for (int j = 0; j < 32; ++j) {
    int n = n0 + half + (j << 1);
    int g = (b*3*NPTS + n)*128 + o;
    float p0 = pF[g], p1 = pF[g + NPTS*128], p2 = pF[g + 2*NPTS*128];
    float nrm = sqrtf(p0*p0 + p1*p1 + p2*p2) + 1e-6f;
    s += nrm; ss = fmaf(nrm, nrm, ss);
  }
  atomicAdd(&statsF[o], s);
  atomicAdd(&statsF[128 + o], ss);
}

__global__ __launch_bounds__(256) void k_final(const float* __restrict__ pF, const float* __restrict__ dF,
                                               const float* __restrict__ statsF,
                                               const float* __restrict__ bncw, const float* __restrict__ bncb,
                                               float* __restrict__ out) {
  int tid = threadIdx.x; int o = tid & 127, half = tid >> 7;
  int blk = blockIdx.x;
  int b = blk >> 3, n0 = (blk & 7) << 7;
  const float cntInv = 1.f / 8192.f;
  float mean = statsF[o] * cntInv;
  float var  = statsF[128 + o] * cntInv - mean*mean;
  float istd = rsqrtf(var + 1e-5f);
  float wN = bncw[o], bN = bncb[o];
  float a0 = 0.f, a1 = 0.f, a2 = 0.f;
  for (int j = 0; j < 64; ++j) {
    int n = n0 + half + (j << 1);
    int g = (b*3*NPTS + n)*128 + o;
    float p0 = pF[g], p1 = pF[g + NPTS*128], p2 = pF[g + 2*NPTS*128];
    int dg = b*N3 + n;
    float d0 = dF[dg], d1 = dF[dg + NPTS], d2 = dF[dg + 2*NPTS];
    float nrm = sqrtf(p0*p0 + p1*p1 + p2*p2) + 1e-6f;
    float sc = ((nrm - mean)*istd*wN + bN) / nrm;
    p0 *= sc; p1 *= sc; p2 *= sc;
    float dot = p0*d0 + p1*d1 + p2*d2;
    float dsq = d0*d0 + d1*d1 + d2*d2;
    float coef = (dot < 0.f) ? (0.8f * dot / (dsq + 1e-6f)) : 0.f;
    a0 += p0 - coef*d0; a1 += p1 - coef*d1; a2 += p2 - coef*d2;
  }
  float scl = 1.f / 1024.f;
  int ob = (b*128 + o)*3;
  atomicAdd(&out[ob],     a0*scl);
  atomicAdd(&out[ob + 1], a1*scl);
  atomicAdd(&out[ob + 2], a2*scl);
}

extern "C" void kernel_launch(void* const* d_in, const int* in_sizes, int n_in,
                              void* d_out, int out_size, void* d_ws, size_t ws_size,
                              hipStream_t stream) {
  (void)in_sizes; (void)n_in; (void)ws_size;
  const float* x = (const float*)d_in[0];
  const float* wF[4]  = {(const float*)d_in[1],  (const float*)d_in[5],
                         (const float*)d_in[9],  (const float*)d_in[13]};
  const float* wD[4]  = {(const float*)d_in[2],  (const float*)d_in[6],
                         (const float*)d_in[10], (const float*)d_in[14]};
  const float* bnW[4] = {(const float*)d_in[3],  (const float*)d_in[7],
                         (const float*)d_in[11], (const float*)d_in[15]};
  const float* bnB[4] = {(const float*)d_in[4],  (const float*)d_in[8],
                         (const float*)d_in[12], (const float*)d_in[16]};
  const float* wcf  = (const float*)d_in[17];
  const float* wcd  = (const float*)d_in[18];
  const float* bncw = (const float*)d_in[19];
  const float* bncb = (const float*)d_in[20];

  float* ws    = (float*)d_ws;
  float* x0    = ws + OFF_X0;
  float* xfeat = ws + OFF_XFEAT;
  float* yAp   = ws + OFF_YAP;
  float* yBp   = ws + OFF_YBP;
  float* yAd   = ws + OFF_YAD;
  float* yBd   = ws + OFF_YBD;
  float* pF    = ws + OFF_PF;   // aliases yAp/yBp (dead by then)
  float* dF    = ws + OFF_DF;   // aliases yAd
  float* xx    = ws + OFF_XX;
  float* wT    = ws + OFF_WCFT;
  float* stats = ws + OFF_STATS;
  int*   idx   = (int*)(ws + OFF_IDX);

  hipMemsetAsync(stats, 0, 5*256*sizeof(float), stream);
  hipMemsetAsync(d_out, 0, (size_t)out_size*sizeof(float), stream);

  k_transpose<<<NB*NPTS/256, 256, 0, stream>>>(x, x0);
  k_wcfT<<<128, 256, 0, stream>>>(wcf, wT);

  for (int L = 0; L < 4; ++L) {
    const float* fin = (L == 0) ? x0 : (xfeat + (L-1)*64*N3);
    int bs = (L == 0) ? N3 : BSX;
    int D  = (L == 0) ? 3 : 192;
    k_xx<<<NB*NPTS/256, 256, 0, stream>>>(fin, bs, D, xx);
    k_knn2<<<512, 512, 0, stream>>>(fin, bs, D, xx, idx);
    if (L == 0) {
      k_linear3<1><<<dim3(16, 24), 256, 0, stream>>>(fin, bs, wF[0], yAp, yBp);
      k_linear3<1><<<dim3(16, 24), 256, 0, stream>>>(fin, bs, wD[0], yAd, yBd);
    } else {
      k_linear3<64><<<dim3(16, 24), 256, 0, stream>>>(fin, bs, wF[L], yAp, yBp);
      k_linear3<64><<<dim3(16, 24), 256, 0, stream>>>(fin, bs, wD[L], yAd, yBd);
    }
    k_stats<<<512, 256, 0, stream>>>(yAp, yBp, idx, stats + L*256);
    k_apply<<<2048, 256, 0, stream>>>(yAp, yBp, yAd, yBd, idx, stats + L*256,
                                      bnW[L], bnB[L], xfeat, L*64);
  }

  k_pF2<<<dim3(32, 24), 256, 0, stream>>>(xfeat, wT, pF);
  k_dF<<<NB*N3/256, 256, 0, stream>>>(xfeat, wcd, dF);
  k_statsF<<<128, 256, 0, stream>>>(pF, stats + 4*256);
  k_final<<<64, 256, 0, stream>>>(pF, dF, stats + 4*256, bncw, bncb, (float*)d_out);
}

// Round 4
// 1019.810 us; speedup vs baseline: 1.2895x; 1.0672x over previous
//
#include <hip/hip_runtime.h>

#define NPTS 1024
#define NB 8
#define KNN 20
#define N3 (3*NPTS)
#define CHT 256           // total concatenated channels
#define BSX (CHT*N3)      // xfeat batch stride (floats)

// ---- workspace layout (float offsets) ----
constexpr int OFF_X0    = 0;                          // [B][3][N]
constexpr int OFF_XFEAT = OFF_X0 + NB*N3;             // [B][256][3][N]
constexpr int OFF_YAP   = OFF_XFEAT + NB*CHT*N3;      // [B][3][N][64]
constexpr int OFF_YBP   = OFF_YAP + NB*N3*64;
constexpr int OFF_YAD   = OFF_YBP + NB*N3*64;
constexpr int OFF_YBD   = OFF_YAD + NB*N3*64;
constexpr int OFF_XX    = OFF_YBD + NB*N3*64;         // [B][N]
constexpr int OFF_WCFT  = OFF_XX + NB*NPTS;           // [256][128]
constexpr int OFF_STATS = OFF_WCFT + 256*128;         // 5 layers x 256
constexpr int OFF_IDX   = OFF_STATS + 5*256;          // int32 [B][N][20]
// final stage aliases (yA*/yB* dead after the layer loop):
constexpr int OFF_PF    = OFF_YAP;                    // [B][3][N][128]
constexpr int OFF_DF    = OFF_YAD;                    // [B][3][N]

// x [B][N][3] -> x0 [B][3][N]
__global__ void k_transpose(const float* __restrict__ x, float* __restrict__ x0) {
  int t = blockIdx.x*256 + threadIdx.x;
  int b = t >> 10, n = t & 1023;
  const float* p = x + t*3;
  x0[b*N3 + n]          = p[0];
  x0[b*N3 + NPTS + n]   = p[1];
  x0[b*N3 + 2*NPTS + n] = p[2];
}

// per-point squared norm; 4 d-groups per point, smem reduce
__global__ __launch_bounds__(256) void k_xx2(const float* __restrict__ Fb, int bs, int D,
                                             float* __restrict__ xx) {
  __shared__ float sm[4][64];
  int tid = threadIdx.x;
  int p = tid & 63, g = tid >> 6;
  int t = blockIdx.x * 64 + p;
  int b = t >> 10, m = t & 1023;
  int s = (D * g) >> 2, e = (D * (g + 1)) >> 2;
  const float* f = Fb + b*bs + m;
  float a = 0.f;
  for (int d = s; d < e; ++d) { float v = f[d*NPTS]; a = fmaf(v, v, a); }
  sm[g][p] = a;
  __syncthreads();
  if (g == 0) xx[t] = ((sm[0][p] + sm[1][p]) + sm[2][p]) + sm[3][p];
}

// kNN: 512 blocks x 512 threads; block = 16 query rows; Gram in regs via LDS tile;
// top-20 via u64-key butterfly, two rows interleaved for ILP.
__global__ __launch_bounds__(512) void k_knn2(const float* __restrict__ Fb, int bs, int D,
                                              const float* __restrict__ xx,
                                              int* __restrict__ idxo) {
  __shared__ float xs[8][NPTS];          // 32 KB
  int g  = blockIdx.x;
  int wg = (g & 7)*64 + (g >> 3);        // XCD swizzle: batch -> one XCD
  int b  = wg >> 6;
  int n0 = (wg & 63) << 4;
  int tid = threadIdx.x;
  int w = tid >> 6, lane = tid & 63;
  const float* f = Fb + b*bs;

  int row0 = n0 + 2*w, row1 = row0 + 1;
  float acc0[16], acc1[16];
  #pragma unroll
  for (int s = 0; s < 16; ++s) { acc0[s] = 0.f; acc1[s] = 0.f; }

  int nt = (D + 7) >> 3;
  for (int t = 0; t < nt; ++t) {
    int d0 = t << 3;
    int cnt = D - d0; if (cnt > 8) cnt = 8;
    __syncthreads();
    #pragma unroll
    for (int u = 0; u < 4; ++u) {
      int e = tid + (u << 9);
      int dd = e >> 8, mq = (e & 255) << 2;
      if (dd < cnt)
        *(float4*)&xs[dd][mq] = *(const float4*)&f[(d0 + dd)*NPTS + mq];
    }
    __syncthreads();
    for (int dd = 0; dd < cnt; ++dd) {
      float rf0 = xs[dd][row0];
      float rf1 = xs[dd][row1];
      #pragma unroll
      for (int s2 = 0; s2 < 4; ++s2) {
        float4 xm = *(const float4*)&xs[dd][(lane << 2) + (s2 << 8)];
        acc0[s2*4+0] = fmaf(rf0, xm.x, acc0[s2*4+0]);
        acc0[s2*4+1] = fmaf(rf0, xm.y, acc0[s2*4+1]);
        acc0[s2*4+2] = fmaf(rf0, xm.z, acc0[s2*4+2]);
        acc0[s2*4+3] = fmaf(rf0, xm.w, acc0[s2*4+3]);
        acc1[s2*4+0] = fmaf(rf1, xm.x, acc1[s2*4+0]);
        acc1[s2*4+1] = fmaf(rf1, xm.y, acc1[s2*4+1]);
        acc1[s2*4+2] = fmaf(rf1, xm.z, acc1[s2*4+2]);
        acc1[s2*4+3] = fmaf(rf1, xm.w, acc1[s2*4+3]);
      }
    }
  }

  // finalize neg-dist (ref op order) and convert to monotone 32-bit order keys
  unsigned ord0[16], ord1[16];
  float xxr0 = xx[b*NPTS + row0];
  float xxr1 = xx[b*NPTS + row1];
  #pragma unroll
  for (int s2 = 0; s2 < 4; ++s2) {
    float4 xv = *(const float4*)&xx[b*NPTS + (lane << 2) + (s2 << 8)];
    float xm4[4] = {xv.x, xv.y, xv.z, xv.w};
    #pragma unroll
    for (int q = 0; q < 4; ++q) {
      int s = s2*4 + q;
      float v0 = (2.f*acc0[s] - xxr0) - xm4[q];
      float v1 = (2.f*acc1[s] - xxr1) - xm4[q];
      unsigned u0 = __float_as_uint(v0);
      unsigned u1 = __float_as_uint(v1);
      ord0[s] = (u0 & 0x80000000u) ? ~u0 : (u0 | 0x80000000u);
      ord1[s] = (u1 & 0x80000000u) ? ~u1 : (u1 | 0x80000000u);
    }
  }

  unsigned base4L = (unsigned)(lane << 2);
  unsigned cl0 = 0xFFFFFFFFu, cl1 = 0xFFFFFFFFu;   // slot-code to clear (winner only)
  int winm0 = 0, winm1 = 0;
  for (int it = 0; it < KNN; ++it) {
    unsigned bo0 = 0u, bc0 = 0u, bo1 = 0u, bc1 = 0u;
    #pragma unroll
    for (int s = 0; s < 16; ++s) {
      const unsigned Cs = (unsigned)(((s >> 2) << 8) | (s & 3));
      unsigned v0 = ord0[s]; v0 = (cl0 == Cs) ? 0u : v0; ord0[s] = v0;
      if (v0 > bo0) { bo0 = v0; bc0 = Cs; }     // strict > : lowest m wins in-lane
      unsigned v1 = ord1[s]; v1 = (cl1 == Cs) ? 0u : v1; ord1[s] = v1;
      if (v1 > bo1) { bo1 = v1; bc1 = Cs; }
    }
    unsigned m0 = base4L + bc0, m1 = base4L + bc1;
    unsigned long long K0 = ((unsigned long long)bo0 << 32) | (unsigned long long)(1023u - m0);
    unsigned long long K1 = ((unsigned long long)bo1 << 32) | (unsigned long long)(1023u - m1);
    unsigned long long myK0 = K0, myK1 = K1;
    #pragma unroll
    for (int off = 1; off < 64; off <<= 1) {
      unsigned long long o0 = __shfl_xor(K0, off, 64);
      unsigned long long o1 = __shfl_xor(K1, off, 64);
      K0 = (o0 > K0) ? o0 : K0;                  // keys unique (m packed) -> no tie
      K1 = (o1 > K1) ? o1 : K1;
    }
    cl0 = (K0 == myK0) ? bc0 : 0xFFFFFFFFu;
    cl1 = (K1 == myK1) ? bc1 : 0xFFFFFFFFu;
    if (lane == it) {
      winm0 = 1023 - (int)(unsigned)(K0 & 0xFFFFFFFFull);
      winm1 = 1023 - (int)(unsigned)(K1 & 0xFFFFFFFFull);
    }
  }
  if (lane < KNN) {
    idxo[(b*NPTS + row0)*KNN + lane] = winm0;
    idxo[(b*NPTS + row1)*KNN + lane] = winm1;
  }
}

// yA[b][v][n][o] = sum_i w[o][i]*x ; yB uses (w[:,DIN:]-w[:,:DIN])
template<int DIN>
__global__ __launch_bounds__(256) void k_linear3(const float* __restrict__ xin, int bsx,
                                                 const float* __restrict__ w,
                                                 float* __restrict__ yA, float* __restrict__ yB) {
  __shared__ float wA[DIN*64], wB[DIN*64];
  int tid = threadIdx.x;
  for (int e = tid; e < 64*DIN; e += 256) {
    int o = e & 63, i = e >> 6;
    float a = w[o*(2*DIN) + i];
    wA[i*64 + o] = a;
    wB[i*64 + o] = w[o*(2*DIN) + DIN + i] - a;
  }
  __syncthreads();
  int o = tid & 63, ns = tid >> 6;
  int b = blockIdx.y / 3, v = blockIdx.y % 3;
  int n0 = blockIdx.x * 64 + ns * 16;
  const float* xb = xin + b*bsx + v*NPTS + n0;
  float ap[16], bp[16];
  #pragma unroll
  for (int j = 0; j < 16; ++j) { ap[j] = 0.f; bp[j] = 0.f; }
  for (int i = 0; i < DIN; ++i) {
    float wa = wA[i*64 + o], wb = wB[i*64 + o];
    #pragma unroll
    for (int q = 0; q < 4; ++q) {
      float4 xv = *(const float4*)&xb[i*N3 + q*4];
      ap[q*4+0] = fmaf(wa, xv.x, ap[q*4+0]); bp[q*4+0] = fmaf(wb, xv.x, bp[q*4+0]);
      ap[q*4+1] = fmaf(wa, xv.y, ap[q*4+1]); bp[q*4+1] = fmaf(wb, xv.y, bp[q*4+1]);
      ap[q*4+2] = fmaf(wa, xv.z, ap[q*4+2]); bp[q*4+2] = fmaf(wb, xv.z, bp[q*4+2]);
      ap[q*4+3] = fmaf(wa, xv.w, ap[q*4+3]); bp[q*4+3] = fmaf(wb, xv.w, bp[q*4+3]);
    }
  }
  int base = ((b*3 + v)*NPTS + n0)*64 + o;
  #pragma unroll
  for (int j = 0; j < 16; ++j) { yA[base + j*64] = ap[j]; yB[base + j*64] = bp[j]; }
}

// per-channel sum/sumsq of ||p||+eps; 2048 blocks, XCD-batch swizzle
__global__ __launch_bounds__(256) void k_stats2(const float* __restrict__ yAp, const float* __restrict__ yBp,
                                                const int* __restrict__ idxo, float* __restrict__ statsL) {
  __shared__ float rs[256], rss[256];
  int tid = threadIdx.x; int o = tid & 63, w = tid >> 6;
  int blk = blockIdx.x;
  int wg = ((blk & 7) << 8) | (blk >> 3);   // batch -> XCD
  int b = wg >> 8;
  int n = ((wg & 255) << 2) + w;
  float s = 0.f, ss = 0.f;
  int i0 = (b*3*NPTS + n)*64 + o;
  float c0 = yBp[i0], c1 = yBp[i0 + NPTS*64], c2 = yBp[i0 + 2*NPTS*64];
  const int* ir = idxo + (b*NPTS + n)*KNN;
  for (int kk = 0; kk < KNN; ++kk) {
    int m = ir[kk];
    int gg = (b*3*NPTS + m)*64 + o;
    float p0 = yAp[gg] + c0;
    float p1 = yAp[gg + NPTS*64] + c1;
    float p2 = yAp[gg + 2*NPTS*64] + c2;
    float nrm = sqrtf(p0*p0 + p1*p1 + p2*p2) + 1e-6f;
    s += nrm; ss = fmaf(nrm, nrm, ss);
  }
  rs[tid] = s; rss[tid] = ss;
  __syncthreads();
  if (tid < 64) {
    float a  = rs[tid]  + rs[tid+64]  + rs[tid+128]  + rs[tid+192];
    float as = rss[tid] + rss[tid+64] + rss[tid+128] + rss[tid+192];
    atomicAdd(&statsL[tid], a);
    atomicAdd(&statsL[128 + tid], as);
  }
}

// BN + directional LeakyReLU + mean over k -> xfeat slice (XCD-batch swizzle)
__global__ __launch_bounds__(256) void k_apply(const float* __restrict__ yAp, const float* __restrict__ yBp,
                                               const float* __restrict__ yAd, const float* __restrict__ yBd,
                                               const int* __restrict__ idxo, const float* __restrict__ statsL,
                                               const float* __restrict__ bnw, const float* __restrict__ bnb,
                                               float* __restrict__ xfeat, int coff) {
  int tid = threadIdx.x; int o = tid & 63, w = tid >> 6;
  int blk = blockIdx.x;
  int wg = ((blk & 7) << 8) | (blk >> 3);
  int b = wg >> 8;
  int n = ((wg & 255) << 2) + w;
  const float cntInv = 1.f / 163840.f;
  float mean = statsL[o] * cntInv;
  float var  = statsL[128 + o] * cntInv - mean*mean;
  float istd = rsqrtf(var + 1e-5f);
  float wN = bnw[o], bN = bnb[o];
  int i0 = (b*3*NPTS + n)*64 + o;
  float cp0 = yBp[i0], cp1 = yBp[i0 + NPTS*64], cp2 = yBp[i0 + 2*NPTS*64];
  float cd0 = yBd[i0], cd1 = yBd[i0 + NPTS*64], cd2 = yBd[i0 + 2*NPTS*64];
  const int* ir = idxo + (b*NPTS + n)*KNN;
  float a0 = 0.f, a1 = 0.f, a2 = 0.f;
  for (int kk = 0; kk < KNN; ++kk) {
    int m = ir[kk];
    int gg = (b*3*NPTS + m)*64 + o;
    float p0 = yAp[gg] + cp0, p1 = yAp[gg + NPTS*64] + cp1, p2 = yAp[gg + 2*NPTS*64] + cp2;
    float d0 = yAd[gg] + cd0, d1 = yAd[gg + NPTS*64] + cd1, d2 = yAd[gg + 2*NPTS*64] + cd2;
    float nrm = sqrtf(p0*p0 + p1*p1 + p2*p2) + 1e-6f;
    float sc = ((nrm - mean)*istd*wN + bN) / nrm;
    p0 *= sc; p1 *= sc; p2 *= sc;
    float dot = p0*d0 + p1*d1 + p2*d2;
    float dsq = d0*d0 + d1*d1 + d2*d2;
    float coef = (dot < 0.f) ? (0.8f * dot / (dsq + 1e-6f)) : 0.f;
    a0 += p0 - coef*d0; a1 += p1 - coef*d1; a2 += p2 - coef*d2;
  }
  int ob = ((b*CHT + coff + o)*3)*NPTS + n;
  xfeat[ob]          = a0 * 0.05f;
  xfeat[ob + NPTS]   = a1 * 0.05f;
  xfeat[ob + 2*NPTS] = a2 * 0.05f;
}

// wcf [128][256] -> wT [256][128]
__global__ void k_wcfT(const float* __restrict__ wcf, float* __restrict__ wT) {
  int e = blockIdx.x*256 + threadIdx.x;
  int o = e >> 8, i = e & 255;
  wT[i*128 + o] = wcf[e];
}

// pF = wcf * cat (LDS-staged x-tile) ; dF = wcd . cat fused on the same tile
__global__ __launch_bounds__(256) void k_pF3(const float* __restrict__ xfeat, const float* __restrict__ wT,
                                             const float* __restrict__ wcd,
                                             float* __restrict__ pF, float* __restrict__ dF) {
  __shared__ float xs[256][32];          // 32 KB
  __shared__ float dpart[8][32];
  int tid = threadIdx.x;
  int b = blockIdx.y / 3, v = blockIdx.y % 3;
  int n0 = blockIdx.x * 32;
  const float* xb = xfeat + b*BSX + v*NPTS + n0;
  #pragma unroll
  for (int u = 0; u < 8; ++u) {
    int e = tid + (u << 8);
    int i = e >> 3, sl = (e & 7) << 2;
    *(float4*)&xs[i][sl] = *(const float4*)&xb[i*N3 + sl];
  }
  __syncthreads();
  int o = tid & 127, h = tid >> 7;
  float a[16];
  #pragma unroll
  for (int j = 0; j < 16; ++j) a[j] = 0.f;
  for (int i = 0; i < 256; ++i) {
    float wv = wT[i*128 + o];
    #pragma unroll
    for (int q = 0; q < 4; ++q) {
      float4 xv = *(const float4*)&xs[i][h*16 + q*4];
      a[q*4+0] = fmaf(wv, xv.x, a[q*4+0]);
      a[q*4+1] = fmaf(wv, xv.y, a[q*4+1]);
      a[q*4+2] = fmaf(wv, xv.z, a[q*4+2]);
      a[q*4+3] = fmaf(wv, xv.w, a[q*4+3]);
    }
  }
  int base = ((b*3 + v)*NPTS + n0 + h*16)*128 + o;
  #pragma unroll
  for (int j = 0; j < 16; ++j) pF[base + j*128] = a[j];
  // fused dF on the staged tile
  int nn = tid & 31, gI = tid >> 5;
  float dp = 0.f;
  for (int i = gI*32; i < gI*32 + 32; ++i) dp = fmaf(wcd[i], xs[i][nn], dp);
  dpart[gI][nn] = dp;
  __syncthreads();
  if (tid < 32) {
    float aa = 0.f;
    #pragma unroll
    for (int gq = 0; gq < 8; ++gq) aa += dpart[gq][tid];
    dF[(b*3 + v)*NPTS + n0 + tid] = aa;
  }
}

__global__ __launch_bounds__(256) void k_statsF2(const float* __restrict__ pF, float* __restrict__ statsF) {
  int tid = threadIdx.x; int o = tid & 127, half = tid >> 7;
  int blk = blockIdx.x;
  int b = blk >> 6, n0 = (blk & 63) << 4;
  float s = 0.f, ss = 0.f;
  for (int j = 0; j < 8; ++j) {
    int n = n0 + half + (j << 1);
    int g = (b*3*NPTS + n)*128 + o;
    float p0 = pF[g], p1 = pF[g + NPTS*128], p2 = pF[g + 2*NPTS*128];
    float nrm = sqrtf(p0*p0 + p1*p1 + p2*p2) + 1e-6f;
    s += nrm; ss = fmaf(nrm, nrm, ss);
  }
  atomicAdd(&statsF[o], s);
  atomicAdd(&statsF[128 + o], ss);
}

__global__ __launch_bounds__(256) void k_final2(const float* __restrict__ pF, const float* __restrict__ dF,
                                                const float* __restrict__ statsF,
                                                const float* __restrict__ bncw, const float* __restrict__ bncb,
                                                float* __restrict__ out) {
  int tid = threadIdx.x; int o = tid & 127, half = tid >> 7;
  int blk = blockIdx.x;
  int b = blk >> 5, n0 = (blk & 31) << 5;
  const float cntInv = 1.f / 8192.f;
  float mean = statsF[o] * cntInv;
  float var  = statsF[128 + o] * cntInv - mean*mean;
  float istd = rsqrtf(var + 1e-5f);
  float wN = bncw[o], bN = bncb[o];
  float a0 = 0.f, a1 = 0.f, a2 = 0.f;
  for (int j = 0; j < 16; ++j) {
    int n = n0 + half + (j << 1);
    int g = (b*3*NPTS + n)*128 + o;
    float p0 = pF[g], p1 = pF[g + NPTS*128], p2 = pF[g + 2*NPTS*128];
    int dg = b*N3 + n;
    float d0 = dF[dg], d1 = dF[dg + NPTS], d2 = dF[dg + 2*NPTS];
    float nrm = sqrtf(p0*p0 + p1*p1 + p2*p2) + 1e-6f;
    float sc = ((nrm - mean)*istd*wN + bN) / nrm;
    p0 *= sc; p1 *= sc; p2 *= sc;
    float dot = p0*d0 + p1*d1 + p2*d2;
    float dsq = d0*d0 + d1*d1 + d2*d2;
    float coef = (dot < 0.f) ? (0.8f * dot / (dsq + 1e-6f)) : 0.f;
    a0 += p0 - coef*d0; a1 += p1 - coef*d1; a2 += p2 - coef*d2;
  }
  float scl = 1.f / 1024.f;
  int ob = (b*128 + o)*3;
  atomicAdd(&out[ob],     a0*scl);
  atomicAdd(&out[ob + 1], a1*scl);
  atomicAdd(&out[ob + 2], a2*scl);
}

extern "C" void kernel_launch(void* const* d_in, const int* in_sizes, int n_in,
                              void* d_out, int out_size, void* d_ws, size_t ws_size,
                              hipStream_t stream) {
  (void)in_sizes; (void)n_in; (void)ws_size;
  const float* x = (const float*)d_in[0];
  const float* wF[4]  = {(const float*)d_in[1],  (const float*)d_in[5],
                         (const float*)d_in[9],  (const float*)d_in[13]};
  const float* wD[4]  = {(const float*)d_in[2],  (const float*)d_in[6],
                         (const float*)d_in[10], (const float*)d_in[14]};
  const float* bnW[4] = {(const float*)d_in[3],  (const float*)d_in[7],
                         (const float*)d_in[11], (const float*)d_in[15]};
  const float* bnB[4] = {(const float*)d_in[4],  (const float*)d_in[8],
                         (const float*)d_in[12], (const float*)d_in[16]};
  const float* wcf  = (const float*)d_in[17];
  const float* wcd  = (const float*)d_in[18];
  const float* bncw = (const float*)d_in[19];
  const float* bncb = (const float*)d_in[20];

  float* ws    = (float*)d_ws;
  float* x0    = ws + OFF_X0;
  float* xfeat = ws + OFF_XFEAT;
  float* yAp   = ws + OFF_YAP;
  float* yBp   = ws + OFF_YBP;
  float* yAd   = ws + OFF_YAD;
  float* yBd   = ws + OFF_YBD;
  float* pF    = ws + OFF_PF;   // aliases yAp/yBp (dead by then)
  float* dF    = ws + OFF_DF;   // aliases yAd
  float* xx    = ws + OFF_XX;
  float* wT    = ws + OFF_WCFT;
  float* stats = ws + OFF_STATS;
  int*   idx   = (int*)(ws + OFF_IDX);

  hipMemsetAsync(stats, 0, 5*256*sizeof(float), stream);
  hipMemsetAsync(d_out, 0, (size_t)out_size*sizeof(float), stream);

  k_transpose<<<NB*NPTS/256, 256, 0, stream>>>(x, x0);
  k_wcfT<<<128, 256, 0, stream>>>(wcf, wT);

  for (int L = 0; L < 4; ++L) {
    const float* fin = (L == 0) ? x0 : (xfeat + (L-1)*64*N3);
    int bs = (L == 0) ? N3 : BSX;
    int D  = (L == 0) ? 3 : 192;
    k_xx2<<<NB*NPTS/64, 256, 0, stream>>>(fin, bs, D, xx);
    k_knn2<<<512, 512, 0, stream>>>(fin, bs, D, xx, idx);
    if (L == 0) {
      k_linear3<1><<<dim3(16, 24), 256, 0, stream>>>(fin, bs, wF[0], yAp, yBp);
      k_linear3<1><<<dim3(16, 24), 256, 0, stream>>>(fin, bs, wD[0], yAd, yBd);
    } else {
      k_linear3<64><<<dim3(16, 24), 256, 0, stream>>>(fin, bs, wF[L], yAp, yBp);
      k_linear3<64><<<dim3(16, 24), 256, 0, stream>>>(fin, bs, wD[L], yAd, yBd);
    }
    k_stats2<<<2048, 256, 0, stream>>>(yAp, yBp, idx, stats + L*256);
    k_apply<<<2048, 256, 0, stream>>>(yAp, yBp, yAd, yBd, idx, stats + L*256,
                                      bnW[L], bnB[L], xfeat, L*64);
  }

  k_pF3<<<dim3(32, 24), 256, 0, stream>>>(xfeat, wT, wcd, pF, dF);
  k_statsF2<<<512, 256, 0, stream>>>(pF, stats + 4*256);
  k_final2<<<256, 256, 0, stream>>>(pF, dF, stats + 4*256, bncw, bncb, (float*)d_out);
}